// Round 1
// baseline (207.310 us; speedup 1.0000x reference)
//
#include <hip/hip_runtime.h>

#define TINYF 1e-8f
#define NITER 50

__device__ __forceinline__ float bperm(int addr4, float v) {
    return __int_as_float(__builtin_amdgcn_ds_bpermute(addr4, __float_as_int(v)));
}
// lane i <- lane i-1 within 16-lane DPP row; 0 at row edge (= crop left edge)
__device__ __forceinline__ float dpp_shr1(float v) {
    return __int_as_float(__builtin_amdgcn_update_dpp(0, __float_as_int(v), 0x111, 0xf, 0xf, true));
}
// lane i <- lane i+1 within 16-lane DPP row; 0 at row edge (= crop right edge)
__device__ __forceinline__ float dpp_shl1(float v) {
    return __int_as_float(__builtin_amdgcn_update_dpp(0, __float_as_int(v), 0x101, 0xf, 0xf, true));
}

// full prep: s1 (|dx|=1 pairs) + s2 (|dx|=2 pairs) for this lane's 3 cols
#define PREPF(C0_, C1_, C2_) \
    L2 = dpp_shr1(C1_); L1 = dpp_shr1(C2_); R1 = dpp_shl1(C0_); R2 = dpp_shl1(C1_); \
    s1a = L1 + C1_; s1b = C0_ + C2_; s1c = C1_ + R1; \
    s2a = L2 + C2_; s2b = L1 + R1; s2c = C0_ + R2;
// s1-only prep (for |dy|=1 halo rows)
#define PREPS(C0_, C1_, C2_) \
    L1 = dpp_shr1(C2_); R1 = dpp_shl1(C0_); \
    s1a = L1 + C1_; s1b = C0_ + C2_; s1c = C1_ + R1;
// dy=0 row: center + |dx|=1 + |dx|=2   (I-variant: first touch; acc=0+t == t)
#define AT0(I, C0_, C1_, C2_, KA, KB, KC) \
    acc[I][0] += KA * C0_ + KB * s1a + KC * s2a; \
    acc[I][1] += KA * C1_ + KB * s1b + KC * s2b; \
    acc[I][2] += KA * C2_ + KB * s1c + KC * s2c;
#define AT0I(I, C0_, C1_, C2_, KA, KB, KC) \
    acc[I][0] = KA * C0_ + KB * s1a + KC * s2a; \
    acc[I][1] = KA * C1_ + KB * s1b + KC * s2b; \
    acc[I][2] = KA * C2_ + KB * s1c + KC * s2c;
// |dy|=1 row: center + |dx|=1 (e5 corner dropped)
#define AT1(I, C0_, C1_, C2_, KA, KB) \
    acc[I][0] += KA * C0_ + KB * s1a; \
    acc[I][1] += KA * C1_ + KB * s1b; \
    acc[I][2] += KA * C2_ + KB * s1c;
#define AT1I(I, C0_, C1_, C2_, KA, KB) \
    acc[I][0] = KA * C0_ + KB * s1a; \
    acc[I][1] = KA * C1_ + KB * s1b; \
    acc[I][2] = KA * C2_ + KB * s1c;
// |dy|=2 row: center only (e5/e8 dropped)
#define AT2(I, C0_, C1_, C2_, KA) \
    acc[I][0] += KA * C0_; \
    acc[I][1] += KA * C1_; \
    acc[I][2] += KA * C2_;
#define AT2I(I, C0_, C1_, C2_, KA) \
    acc[I][0] = KA * C0_; \
    acc[I][1] = KA * C1_; \
    acc[I][2] = KA * C2_;

// One wave = one full 48x48 crop. Lane layout: b = l>>4 -> row band (12 rows),
// c = l&15 -> col group (3 cols). Vertical halos between bands via ds_bpermute
// (lane +/-16), crop top/bottom edges are zeros. NO barriers, NO LDS staging.
__global__ void __launch_bounds__(64)
__attribute__((amdgpu_waves_per_eu(1, 1)))
sinkhorn_1w(const float* __restrict__ hm_gt,
            const float* __restrict__ hm_pred,
            const int* __restrict__ tops,
            float* __restrict__ out) {
    const int l = threadIdx.x & 63;
    const int b = l >> 4, c = l & 15;      // band (12 rows) x colgroup (3 cols)
    const bool btop = (b == 0), bbot = (b == 3);
    const int upA = ((l - 16) & 63) << 2;
    const int dnA = ((l + 16) & 63) << 2;

    const int blk = blockIdx.x;            // ((bi*8+rr)*5+cc)
    const int bi = blk / 40, rr = (blk / 5) % 8, cc = blk % 5;
    const int y0 = tops[(bi * 8 + rr) * 2 + 0];
    const int x0 = tops[(bi * 8 + rr) * 2 + 1];
    const float* srcA = hm_gt + (size_t)(bi * 5 + cc) * 25600;
    const float* srcB = hm_pred + (size_t)(bi * 5 + cc) * 25600;

    // ---- load own 12x3 tiles of both crops; wave-reduce sums ----
    float va[12][3], vb[12][3];
    float sA = 0.f, sB = 0.f;
    const int rbase = y0 + 12 * b;
#pragma unroll
    for (int i = 0; i < 12; ++i) {
        const int g = (rbase + i) * 160 + x0 + 3 * c;
#pragma unroll
        for (int j = 0; j < 3; ++j) {
            const float A = srcA[g + j];
            const float B = srcB[g + j];
            va[i][j] = A; vb[i][j] = B;
            sA += A; sB += B;
        }
    }
#pragma unroll
    for (int o = 1; o < 64; o <<= 1) {
        sA += __shfl_xor(sA, o, 64);
        sB += __shfl_xor(sB, o, 64);
    }
    const float nA = 1.0f / (sA + TINYF);
    const float nB = 1.0f / (sB + TINYF);
#pragma unroll
    for (int i = 0; i < 12; ++i)
#pragma unroll
        for (int j = 0; j < 3; ++j) { va[i][j] *= nA; vb[i][j] *= nB; }

    // Gibbs weights (same expressions as before -> same rounding)
    const float e10 = expf(-1.0f / 0.1f);
    const float e2  = expf(-sqrtf(2.0f) / 0.1f);
    const float e20 = expf(-2.0f / 0.1f);

    float xu[12][3], xv[12][3], acc[12][3];
    const float u0 = 1.0f / 2304.0f;
#pragma unroll
    for (int i = 0; i < 12; ++i)
#pragma unroll
        for (int j = 0; j < 3; ++j) xu[i][j] = u0;

    // 13-tap conv (center, 4x e10, 4x e2, 4x e20). Vertical halos intra-wave
    // via bperm (band +/-1); zeros at crop top/bottom. bperms hoisted to the
    // top so their LDS-transit latency hides under the 12 own-row FMA stream.
    auto conv = [&](const float (&x)[12][3],
                    float K00, float K01, float K02,
                    float K10, float K11, float K20) {
        float tA[3], tB[3], tC[3], tD[3];
#pragma unroll
        for (int j = 0; j < 3; ++j) {
            tA[j] = bperm(upA, x[10][j]);  // row -2 candidate
            tB[j] = bperm(upA, x[11][j]);  // row -1
            tC[j] = bperm(dnA, x[0][j]);   // row 12
            tD[j] = bperm(dnA, x[1][j]);   // row 13
        }

        float L1, L2, R1, R2, s1a, s1b, s1c, s2a, s2b, s2c;
#pragma unroll
        for (int w = 0; w < 12; ++w) {
            PREPF(x[w][0], x[w][1], x[w][2])
            if (w == 0) {
                AT0I(0, x[0][0], x[0][1], x[0][2], K00, K01, K02)
                AT1I(1, x[0][0], x[0][1], x[0][2], K10, K11)
                AT2I(2, x[0][0], x[0][1], x[0][2], K20)
            } else {
                if (w >= 2) { AT2(w - 2, x[w][0], x[w][1], x[w][2], K20) }
                AT1(w - 1, x[w][0], x[w][1], x[w][2], K10, K11)
                AT0(w, x[w][0], x[w][1], x[w][2], K00, K01, K02)
                if (w <= 10) { AT1(w + 1, x[w][0], x[w][1], x[w][2], K10, K11) }
                if (w <= 9)  { AT2I(w + 2, x[w][0], x[w][1], x[w][2], K20) }
            }
        }

        // resolve halos (crop edges -> 0)
        float hA[3], hB[3], hC[3], hD[3];
#pragma unroll
        for (int j = 0; j < 3; ++j) {
            hA[j] = btop ? 0.f : tA[j];
            hB[j] = btop ? 0.f : tB[j];
            hC[j] = bbot ? 0.f : tC[j];
            hD[j] = bbot ? 0.f : tD[j];
        }
        // halo-row contributions (hA/hD: center tap only -> no DPP prep)
        PREPS(hB[0], hB[1], hB[2])          // row -1
        AT1(0, hB[0], hB[1], hB[2], K10, K11)
        AT2(1, hB[0], hB[1], hB[2], K20)
        AT2(0, hA[0], hA[1], hA[2], K20)    // row -2
        PREPS(hC[0], hC[1], hC[2])          // row 12
        AT2(10, hC[0], hC[1], hC[2], K20)
        AT1(11, hC[0], hC[1], hC[2], K10, K11)
        AT2(11, hD[0], hD[1], hD[2], K20)   // row 13
    };

    // ---- Sinkhorn iterations: zero barriers, fully in-wave ----
#pragma unroll 1
    for (int it = 0; it < NITER; ++it) {
        conv(xu, 1.0f, e10, e20, e10, e2, e20);
#pragma unroll
        for (int i = 0; i < 12; ++i)
#pragma unroll
            for (int j = 0; j < 3; ++j)
                xv[i][j] = vb[i][j] * __builtin_amdgcn_rcpf(acc[i][j] + TINYF);

        conv(xv, 1.0f, e10, e20, e10, e2, e20);
#pragma unroll
        for (int i = 0; i < 12; ++i)
#pragma unroll
            for (int j = 0; j < 3; ++j)
                xu[i][j] = va[i][j] * __builtin_amdgcn_rcpf(acc[i][j] + TINYF);
    }

    // ---- loss: (u @ M) . v, M = K .* dist (center 0; e5/e8 taps dropped) ----
    const float s2f = sqrtf(2.0f);
    const float m01 = e10, m02 = e20 * 2.0f, m11 = e2 * s2f;
    conv(xu, 0.0f, m01, m02, m01, m11, m02);
    float lsum = 0.f;
#pragma unroll
    for (int i = 0; i < 12; ++i)
#pragma unroll
        for (int j = 0; j < 3; ++j)
            lsum += acc[i][j] * xv[i][j];

#pragma unroll
    for (int o = 1; o < 64; o <<= 1) lsum += __shfl_xor(lsum, o, 64);
    if (l == 0) atomicAdd(out, lsum);
}

extern "C" void kernel_launch(void* const* d_in, const int* in_sizes, int n_in,
                              void* d_out, int out_size, void* d_ws, size_t ws_size,
                              hipStream_t stream) {
    (void)in_sizes; (void)n_in; (void)out_size; (void)d_ws; (void)ws_size;
    const float* hm_gt = (const float*)d_in[0];
    const float* hm_pred = (const float*)d_in[1];
    const int* tops = (const int*)d_in[2];
    float* out = (float*)d_out;

    hipMemsetAsync(out, 0, sizeof(float), stream);
    sinkhorn_1w<<<dim3(640), dim3(64), 0, stream>>>(hm_gt, hm_pred, tops, out);
}

// Round 2
// 198.406 us; speedup vs baseline: 1.0449x; 1.0449x over previous
//
#include <hip/hip_runtime.h>

#define TINYF 1e-8f
#define NITER 50

__device__ __forceinline__ float bperm(int addr4, float v) {
    return __int_as_float(__builtin_amdgcn_ds_bpermute(addr4, __float_as_int(v)));
}
// lane i <- lane i-1 within 16-lane DPP row; 0 at row edge (= crop left edge)
__device__ __forceinline__ float dpp_shr1(float v) {
    return __int_as_float(__builtin_amdgcn_update_dpp(0, __float_as_int(v), 0x111, 0xf, 0xf, true));
}
// lane i <- lane i+1 within 16-lane DPP row; 0 at row edge (= crop right edge)
__device__ __forceinline__ float dpp_shl1(float v) {
    return __int_as_float(__builtin_amdgcn_update_dpp(0, __float_as_int(v), 0x101, 0xf, 0xf, true));
}

// full prep: s1 (|dx|=1 pairs) + s2 (|dx|=2 pairs) for this lane's 3 cols
#define PREPF(C0_, C1_, C2_) \
    L2 = dpp_shr1(C1_); L1 = dpp_shr1(C2_); R1 = dpp_shl1(C0_); R2 = dpp_shl1(C1_); \
    s1a = L1 + C1_; s1b = C0_ + C2_; s1c = C1_ + R1; \
    s2a = L2 + C2_; s2b = L1 + R1; s2c = C0_ + R2;
// s1-only prep (for |dy|=1 halo rows)
#define PREPS(C0_, C1_, C2_) \
    L1 = dpp_shr1(C2_); R1 = dpp_shl1(C0_); \
    s1a = L1 + C1_; s1b = C0_ + C2_; s1c = C1_ + R1;
// dy=0 row: center + |dx|=1 + |dx|=2   (I-variant: first touch)
#define AT0(I, C0_, C1_, C2_, KA, KB, KC) \
    acc[I][0] += KA * C0_ + KB * s1a + KC * s2a; \
    acc[I][1] += KA * C1_ + KB * s1b + KC * s2b; \
    acc[I][2] += KA * C2_ + KB * s1c + KC * s2c;
#define AT0I(I, C0_, C1_, C2_, KA, KB, KC) \
    acc[I][0] = KA * C0_ + KB * s1a + KC * s2a; \
    acc[I][1] = KA * C1_ + KB * s1b + KC * s2b; \
    acc[I][2] = KA * C2_ + KB * s1c + KC * s2c;
// |dy|=1 row: center + |dx|=1 (e5 corner dropped)
#define AT1(I, C0_, C1_, C2_, KA, KB) \
    acc[I][0] += KA * C0_ + KB * s1a; \
    acc[I][1] += KA * C1_ + KB * s1b; \
    acc[I][2] += KA * C2_ + KB * s1c;
#define AT1I(I, C0_, C1_, C2_, KA, KB) \
    acc[I][0] = KA * C0_ + KB * s1a; \
    acc[I][1] = KA * C1_ + KB * s1b; \
    acc[I][2] = KA * C2_ + KB * s1c;
// |dy|=2 row: center only (e5/e8 dropped)
#define AT2(I, C0_, C1_, C2_, KA) \
    acc[I][0] += KA * C0_; \
    acc[I][1] += KA * C1_; \
    acc[I][2] += KA * C2_;
#define AT2I(I, C0_, C1_, C2_, KA) \
    acc[I][0] = KA * C0_; \
    acc[I][1] = KA * C1_; \
    acc[I][2] = KA * C2_;

// 4 waves = one 48x48 crop; wave W owns rows [12W, 12W+12). Lane: b = l>>4 ->
// 3-row band, c = l&15 -> 3-col group. Band halos intra-wave via ds_bpermute
// (lane +/-16); wave-boundary halos via parity-double-buffered EX in LDS with
// ONE barrier per half-iteration. 2560 waves total -> ~2.5 waves/SIMD of TLP
// to hide bperm/FMA dependency latency (Round-1 lesson: that latency, not
// barriers, was the stall).
__global__ void __launch_bounds__(256)
sinkhorn_4w(const float* __restrict__ hm_gt,
            const float* __restrict__ hm_pred,
            const int* __restrict__ tops,
            float* __restrict__ out) {
    // EX[parity][wave][slot][lane16*4]; slots 0,1 = wave rows 0,1 (for wave W-1);
    // slots 2,3 = wave rows 10,11 (for wave W+1).
    __shared__ __align__(16) float EX[2][4][4][64];
    __shared__ float sred[2][4];

    const int t = threadIdx.x;
    const int W = t >> 6;                  // wave 0..3
    const int l = t & 63;
    const int b = l >> 4, c = l & 15;      // band (3 rows) x colgroup (3 cols)
    const bool btop = (b == 0), bbot = (b == 3);
    const bool wtop = (W == 0), wbot = (W == 3);
    const int upA = ((l - 16) & 63) << 2;
    const int dnA = ((l + 16) & 63) << 2;

    const int blk = blockIdx.x;            // ((bi*8+rr)*5+cc)
    const int bi = blk / 40, rr = (blk / 5) % 8, cc = blk % 5;
    const int y0 = tops[(bi * 8 + rr) * 2 + 0];
    const int x0 = tops[(bi * 8 + rr) * 2 + 1];
    const float* srcA = hm_gt + (size_t)(bi * 5 + cc) * 25600;
    const float* srcB = hm_pred + (size_t)(bi * 5 + cc) * 25600;

    // ---- load own 3x3 tiles of both crops; block-reduce sums ----
    float va[3][3], vb[3][3];
    float sA = 0.f, sB = 0.f;
    const int rbase = y0 + 12 * W + 3 * b;
#pragma unroll
    for (int i = 0; i < 3; ++i) {
        const int g = (rbase + i) * 160 + x0 + 3 * c;
#pragma unroll
        for (int j = 0; j < 3; ++j) {
            const float A = srcA[g + j];
            const float B = srcB[g + j];
            va[i][j] = A; vb[i][j] = B;
            sA += A; sB += B;
        }
    }
#pragma unroll
    for (int o = 1; o < 64; o <<= 1) {
        sA += __shfl_xor(sA, o, 64);
        sB += __shfl_xor(sB, o, 64);
    }
    if (l == 0) { sred[0][W] = sA; sred[1][W] = sB; }
    __syncthreads();
    sA = sred[0][0] + sred[0][1] + sred[0][2] + sred[0][3];
    sB = sred[1][0] + sred[1][1] + sred[1][2] + sred[1][3];
    const float nA = 1.0f / (sA + TINYF);
    const float nB = 1.0f / (sB + TINYF);
#pragma unroll
    for (int i = 0; i < 3; ++i)
#pragma unroll
        for (int j = 0; j < 3; ++j) { va[i][j] *= nA; vb[i][j] *= nB; }

    // Gibbs weights (same expressions as before -> same rounding)
    const float e10 = expf(-1.0f / 0.1f);
    const float e2  = expf(-sqrtf(2.0f) / 0.1f);
    const float e20 = expf(-2.0f / 0.1f);

    float xu[3][3], xv[3][3], acc[3][3];
    const float u0 = 1.0f / 2304.0f;
#pragma unroll
    for (int i = 0; i < 3; ++i)
#pragma unroll
        for (int j = 0; j < 3; ++j) xu[i][j] = u0;

    // publish boundary rows of field y into parity buffer p, then sync
    auto publish = [&](const float (&y)[3][3], int p) {
        if (btop) {
            *(float4*)&EX[p][W][0][c * 4] = make_float4(y[0][0], y[0][1], y[0][2], 0.f);
            *(float4*)&EX[p][W][1][c * 4] = make_float4(y[1][0], y[1][1], y[1][2], 0.f);
        }
        if (bbot) {
            *(float4*)&EX[p][W][2][c * 4] = make_float4(y[1][0], y[1][1], y[1][2], 0.f);
            *(float4*)&EX[p][W][3][c * 4] = make_float4(y[2][0], y[2][1], y[2][2], 0.f);
        }
        __syncthreads();
    };

    // 13-tap conv (center, 4x e10, 4x e2, 4x e20). LDS boundary reads issued
    // first, bperms second, then own-row FMA stream hides their latency.
    auto conv = [&](const float (&x)[3][3], int p,
                    float K00, float K01, float K02,
                    float K10, float K11, float K20) {
        float qA[3] = {0.f, 0.f, 0.f}, qB[3] = {0.f, 0.f, 0.f};
        float qC[3] = {0.f, 0.f, 0.f}, qD[3] = {0.f, 0.f, 0.f};
        if (btop && !wtop) {
            float4 f0 = *(const float4*)&EX[p][W - 1][2][c * 4];   // crop row 12W-2
            float4 f1 = *(const float4*)&EX[p][W - 1][3][c * 4];   // crop row 12W-1
            qA[0] = f0.x; qA[1] = f0.y; qA[2] = f0.z;
            qB[0] = f1.x; qB[1] = f1.y; qB[2] = f1.z;
        }
        if (bbot && !wbot) {
            float4 f0 = *(const float4*)&EX[p][W + 1][0][c * 4];   // crop row 12W+12
            float4 f1 = *(const float4*)&EX[p][W + 1][1][c * 4];   // crop row 12W+13
            qC[0] = f0.x; qC[1] = f0.y; qC[2] = f0.z;
            qD[0] = f1.x; qD[1] = f1.y; qD[2] = f1.z;
        }
        float tA[3], tB[3], tC[3], tD[3];
#pragma unroll
        for (int j = 0; j < 3; ++j) {
            tA[j] = bperm(upA, x[1][j]);   // band-1 row 1 = local row -2
            tB[j] = bperm(upA, x[2][j]);   // local row -1
            tC[j] = bperm(dnA, x[0][j]);   // local row 3
            tD[j] = bperm(dnA, x[1][j]);   // local row 4
        }

        float L1, L2, R1, R2, s1a, s1b, s1c, s2a, s2b, s2c;
        // own rows (no DS dependence -> hides LDS/bperm latency)
        PREPF(x[0][0], x[0][1], x[0][2])                        // w=0
        AT0I(0, x[0][0], x[0][1], x[0][2], K00, K01, K02)
        AT1I(1, x[0][0], x[0][1], x[0][2], K10, K11)
        AT2I(2, x[0][0], x[0][1], x[0][2], K20)
        PREPF(x[1][0], x[1][1], x[1][2])                        // w=1
        AT1(0, x[1][0], x[1][1], x[1][2], K10, K11)
        AT0(1, x[1][0], x[1][1], x[1][2], K00, K01, K02)
        AT1(2, x[1][0], x[1][1], x[1][2], K10, K11)
        PREPF(x[2][0], x[2][1], x[2][2])                        // w=2
        AT2(0, x[2][0], x[2][1], x[2][2], K20)
        AT1(1, x[2][0], x[2][1], x[2][2], K10, K11)
        AT0(2, x[2][0], x[2][1], x[2][2], K00, K01, K02)

        // resolve halos (band edge: intra-wave bperm or inter-wave LDS / zero)
        float hA[3], hB[3], hC[3], hD[3];
#pragma unroll
        for (int j = 0; j < 3; ++j) {
            hA[j] = btop ? qA[j] : tA[j];
            hB[j] = btop ? qB[j] : tB[j];
            hC[j] = bbot ? qC[j] : tC[j];
            hD[j] = bbot ? qD[j] : tD[j];
        }
        // halo-row contributions (hA/hD: center tap only -> no DPP prep)
        PREPS(hB[0], hB[1], hB[2])          // row -1
        AT1(0, hB[0], hB[1], hB[2], K10, K11)
        AT2(1, hB[0], hB[1], hB[2], K20)
        AT2(0, hA[0], hA[1], hA[2], K20)    // row -2
        PREPS(hC[0], hC[1], hC[2])          // row 3
        AT2(1, hC[0], hC[1], hC[2], K20)
        AT1(2, hC[0], hC[1], hC[2], K10, K11)
        AT2(2, hD[0], hD[1], hD[2], K20)    // row 4
    };

    // seed parity-0 buffer with u0 boundary rows
    publish(xu, 0);

    // ---- Sinkhorn iterations: 1 barrier per half-iteration ----
#pragma unroll 1
    for (int it = 0; it < NITER; ++it) {
        conv(xu, 0, 1.0f, e10, e20, e10, e2, e20);
#pragma unroll
        for (int i = 0; i < 3; ++i)
#pragma unroll
            for (int j = 0; j < 3; ++j)
                xv[i][j] = vb[i][j] * __builtin_amdgcn_rcpf(acc[i][j] + TINYF);
        publish(xv, 1);

        conv(xv, 1, 1.0f, e10, e20, e10, e2, e20);
#pragma unroll
        for (int i = 0; i < 3; ++i)
#pragma unroll
            for (int j = 0; j < 3; ++j)
                xu[i][j] = va[i][j] * __builtin_amdgcn_rcpf(acc[i][j] + TINYF);
        publish(xu, 0);
    }

    // ---- loss: (u @ M) . v, M = K .* dist (center 0; e5/e8 taps dropped) ----
    const float s2f = sqrtf(2.0f);
    const float m01 = e10, m02 = e20 * 2.0f, m11 = e2 * s2f;
    conv(xu, 0, 0.0f, m01, m02, m01, m11, m02);
    float lsum = 0.f;
#pragma unroll
    for (int i = 0; i < 3; ++i)
#pragma unroll
        for (int j = 0; j < 3; ++j)
            lsum += acc[i][j] * xv[i][j];

#pragma unroll
    for (int o = 1; o < 64; o <<= 1) lsum += __shfl_xor(lsum, o, 64);
    if (l == 0) sred[0][W] = lsum;
    __syncthreads();
    if (t == 0)
        atomicAdd(out, sred[0][0] + sred[0][1] + sred[0][2] + sred[0][3]);
}

extern "C" void kernel_launch(void* const* d_in, const int* in_sizes, int n_in,
                              void* d_out, int out_size, void* d_ws, size_t ws_size,
                              hipStream_t stream) {
    (void)in_sizes; (void)n_in; (void)out_size; (void)d_ws; (void)ws_size;
    const float* hm_gt = (const float*)d_in[0];
    const float* hm_pred = (const float*)d_in[1];
    const int* tops = (const int*)d_in[2];
    float* out = (float*)d_out;

    hipMemsetAsync(out, 0, sizeof(float), stream);
    sinkhorn_4w<<<dim3(640), dim3(256), 0, stream>>>(hm_gt, hm_pred, tops, out);
}